// Round 2
// baseline (320.930 us; speedup 1.0000x reference)
//
#include <hip/hip_runtime.h>

#define HEADS 4
#define OUT_CH 16
#define CCH 64            // HEADS*OUT_CH
#define IN_CH 128
#define NEG_SLOPE 0.2f

// ---------------------------------------------------------------------------
// GEMM: h[N][64] = x[N][128] @ w[128][64]  (f32 vector ALU; no fp32 MFMA)
// One wave per row: lane = output channel. Weight staged in LDS.
// Epilogue: d_i[n][h] = h[n]·att_i[h], d_j[n][h] = h[n]·att_j[h]
// ---------------------------------------------------------------------------
__global__ __launch_bounds__(256) void gat_gemm(const float* __restrict__ x,
                                                const float* __restrict__ w,
                                                const float* __restrict__ att,
                                                float* __restrict__ h,
                                                float* __restrict__ d_i,
                                                float* __restrict__ d_j, int N) {
    __shared__ float wlds[IN_CH * CCH];
    int t = threadIdx.x;
    #pragma unroll
    for (int i = 0; i < (IN_CH * CCH) / 256; ++i)
        wlds[t + i * 256] = w[t + i * 256];
    __syncthreads();

    int lane = t & 63;
    int row = blockIdx.x * 4 + (t >> 6);
    if (row >= N) return;

    const float* xr = x + (long long)row * IN_CH;
    float acc = 0.f;
    #pragma unroll 8
    for (int k = 0; k < IN_CH; ++k)
        acc = fmaf(xr[k], wlds[k * CCH + lane], acc);
    h[(long long)row * CCH + lane] = acc;

    // epilogue: per-head dots with att_i / att_j
    int head = lane >> 4, ch = lane & 15;
    float si = acc * att[head * (2 * OUT_CH) + ch];
    float sj = acc * att[head * (2 * OUT_CH) + OUT_CH + ch];
    #pragma unroll
    for (int off = 1; off < 16; off <<= 1) {
        si += __shfl_xor(si, off);
        sj += __shfl_xor(sj, off);
    }
    if (ch == 0) {
        d_i[row * HEADS + head] = si;
        d_j[row * HEADS + head] = sj;
    }
}

// ---------------------------------------------------------------------------
// CSR build: zero degrees, histogram by col, exclusive scan, scatter rows
// ---------------------------------------------------------------------------
__global__ void k_zero(int* __restrict__ deg, int N) {
    int i = blockIdx.x * blockDim.x + threadIdx.x;
    if (i < N) deg[i] = 0;
}

__global__ void k_count(const int* __restrict__ cols, int* __restrict__ deg,
                        int E, int N) {
    int e = blockIdx.x * blockDim.x + threadIdx.x;
    if (e >= E + N) return;
    int c = (e < E) ? cols[e] : (e - E);
    atomicAdd(&deg[c], 1);
}

// single-block exclusive scan (N up to ~1M): 1024 threads, wave-shfl based
__global__ __launch_bounds__(1024) void k_scan(const int* __restrict__ deg,
                                               int* __restrict__ offs,
                                               int* __restrict__ cur, int N) {
    __shared__ int wsum[16];
    __shared__ int s_carry;
    int t = threadIdx.x;
    int lane = t & 63, wid = t >> 6;
    if (t == 0) s_carry = 0;
    __syncthreads();
    for (int base = 0; base < N; base += 1024) {
        int idx = base + t;
        int v = (idx < N) ? deg[idx] : 0;
        int xv = v;
        #pragma unroll
        for (int off = 1; off < 64; off <<= 1) {
            int u = __shfl_up(xv, off);
            if (lane >= off) xv += u;
        }
        if (lane == 63) wsum[wid] = xv;
        __syncthreads();
        if (wid == 0) {
            int ws = (lane < 16) ? wsum[lane] : 0;
            #pragma unroll
            for (int off = 1; off < 16; off <<= 1) {
                int u = __shfl_up(ws, off);
                if (lane >= off) ws += u;
            }
            if (lane < 16) wsum[lane] = ws;
        }
        __syncthreads();
        int wbase = (wid == 0) ? 0 : wsum[wid - 1];
        int excl = s_carry + wbase + xv - v;
        if (idx < N) { offs[idx] = excl; cur[idx] = excl; }
        __syncthreads();
        if (t == 0) s_carry += wsum[15];
        __syncthreads();
    }
    if (t == 0) offs[N] = s_carry;
}

__global__ void k_scatter(const int* __restrict__ rows, const int* __restrict__ cols,
                          int* __restrict__ cur, int* __restrict__ srow,
                          int E, int N) {
    int e = blockIdx.x * blockDim.x + threadIdx.x;
    if (e >= E + N) return;
    int r, c;
    if (e < E) { r = rows[e]; c = cols[e]; }
    else       { r = e - E;   c = r; }
    int pos = atomicAdd(&cur[c], 1);
    srow[pos] = r;
}

// ---------------------------------------------------------------------------
// Accumulate: one wave per destination node c. lane = channel, head = lane>>4.
//   alpha_h = softmax_h( leaky( d_i[r,h] + d_j[c,h] ) )
//   out[c]  = sum_r h[r] * alpha_head(ch)  + bias
// ---------------------------------------------------------------------------
__global__ __launch_bounds__(256) void k_accum(const int* __restrict__ offs,
                                               const int* __restrict__ srow,
                                               const float* __restrict__ h,
                                               const float* __restrict__ d_i,
                                               const float* __restrict__ d_j,
                                               const float* __restrict__ bias,
                                               float* __restrict__ out, int N) {
    int c = blockIdx.x * 4 + (threadIdx.x >> 6);
    if (c >= N) return;
    int lane = threadIdx.x & 63;
    int head = lane >> 4;

    float djc = d_j[c * HEADS + head];
    int s = offs[c], e = offs[c + 1];
    float acc = 0.f;
    for (int i = s; i < e; ++i) {
        int r = srow[i];
        float xi = h[(long long)r * CCH + lane];
        float a = d_i[r * HEADS + head] + djc;
        a = a > 0.f ? a : NEG_SLOPE * a;
        float m = fmaxf(a, __shfl_xor(a, 16));
        m = fmaxf(m, __shfl_xor(m, 32));
        float ex = __expf(a - m);
        float sm = ex + __shfl_xor(ex, 16);
        sm += __shfl_xor(sm, 32);
        acc = fmaf(xi, ex * __builtin_amdgcn_rcpf(sm), acc);
    }
    out[(long long)c * CCH + lane] = acc + bias[lane];
}

extern "C" void kernel_launch(void* const* d_in, const int* in_sizes, int n_in,
                              void* d_out, int out_size, void* d_ws, size_t ws_size,
                              hipStream_t stream) {
    const float* x    = (const float*)d_in[0];
    const int*   ei   = (const int*)  d_in[1];
    const float* w    = (const float*)d_in[2];
    const float* att  = (const float*)d_in[3];
    const float* bias = (const float*)d_in[4];
    float* out = (float*)d_out;

    int N = in_sizes[0] / IN_CH;
    int E = in_sizes[1] / 2;
    const int* rows = ei;
    const int* cols = ei + E;

    // workspace layout
    char* ws = (char*)d_ws;
    float* h   = (float*)ws;                 ws += (size_t)N * CCH * 4;    // 12.8 MB
    float* di  = (float*)ws;                 ws += (size_t)N * HEADS * 4;  // 0.8 MB
    float* dj  = (float*)ws;                 ws += (size_t)N * HEADS * 4;  // 0.8 MB
    int*   deg = (int*)ws;                   ws += (size_t)N * 4;
    int*   offs= (int*)ws;                   ws += (size_t)(N + 1) * 4;
    int*   cur = (int*)ws;                   ws += (size_t)N * 4;
    int*   srow= (int*)ws;                   ws += (size_t)(E + N) * 4;    // 3.4 MB

    int total_e = E + N;

    k_zero<<<(N + 255) / 256, 256, 0, stream>>>(deg, N);
    gat_gemm<<<(N + 3) / 4, 256, 0, stream>>>(x, w, att, h, di, dj, N);
    k_count<<<(total_e + 255) / 256, 256, 0, stream>>>(cols, deg, E, N);
    k_scan<<<1, 1024, 0, stream>>>(deg, offs, cur, N);
    k_scatter<<<(total_e + 255) / 256, 256, 0, stream>>>(rows, cols, cur, srow, E, N);
    k_accum<<<(N + 3) / 4, 256, 0, stream>>>(offs, srow, h, di, dj, bias, out, N);
}

// Round 3
// 184.299 us; speedup vs baseline: 1.7414x; 1.7414x over previous
//
#include <hip/hip_runtime.h>

#define HEADS 4
#define OUT_CH 16
#define CCH 64            // HEADS*OUT_CH
#define IN_CH 128
#define NEG_SLOPE 0.2f

// ---------------------------------------------------------------------------
// GEMM: h[N][64] = x[N][128] @ w[128][64]. W column in 128 VGPRs per lane;
// x row read via scalar loads (row made wave-uniform with readfirstlane).
// Epilogue: d_i[n][h] = h[n]·att_i[h], d_j[n][h] = h[n]·att_j[h]
// ---------------------------------------------------------------------------
__global__ __launch_bounds__(256) void gat_gemm(const float* __restrict__ x,
                                                const float* __restrict__ w,
                                                const float* __restrict__ att,
                                                float* __restrict__ h,
                                                float* __restrict__ d_i,
                                                float* __restrict__ d_j, int N) {
    int lane = threadIdx.x & 63;
    int gwave = blockIdx.x * 4 + (threadIdx.x >> 6);
    int nwaves = gridDim.x * 4;

    float wreg[IN_CH];
    #pragma unroll
    for (int k = 0; k < IN_CH; ++k) wreg[k] = w[k * CCH + lane];

    int head = lane >> 4, ch = lane & 15;
    float ai = att[head * (2 * OUT_CH) + ch];
    float aj = att[head * (2 * OUT_CH) + OUT_CH + ch];

    for (int row = gwave; row < N; row += nwaves) {
        int urow = __builtin_amdgcn_readfirstlane(row);
        const float* xr = x + (size_t)urow * IN_CH;
        float a0 = 0.f, a1 = 0.f, a2 = 0.f, a3 = 0.f;
        #pragma unroll
        for (int k = 0; k < IN_CH; k += 4) {
            a0 = fmaf(xr[k + 0], wreg[k + 0], a0);
            a1 = fmaf(xr[k + 1], wreg[k + 1], a1);
            a2 = fmaf(xr[k + 2], wreg[k + 2], a2);
            a3 = fmaf(xr[k + 3], wreg[k + 3], a3);
        }
        float acc = (a0 + a1) + (a2 + a3);
        h[(size_t)urow * CCH + lane] = acc;

        float si = acc * ai, sj = acc * aj;
        #pragma unroll
        for (int off = 1; off < 16; off <<= 1) {
            si += __shfl_xor(si, off);
            sj += __shfl_xor(sj, off);
        }
        if (ch == 0) {
            d_i[urow * HEADS + head] = si;
            d_j[urow * HEADS + head] = sj;
        }
    }
}

// ---------------------------------------------------------------------------
// CSR build
// ---------------------------------------------------------------------------
__global__ void k_zero(int* __restrict__ deg, int Npad) {
    int i = blockIdx.x * blockDim.x + threadIdx.x;
    if (i < Npad) deg[i] = 0;
}

__global__ void k_count(const int* __restrict__ cols, int* __restrict__ deg,
                        int E, int N) {
    int e = blockIdx.x * blockDim.x + threadIdx.x;
    if (e >= E + N) return;
    int c = (e < E) ? cols[e] : (e - E);
    atomicAdd(&deg[c], 1);
}

// phase 1: per-block (1024 elems) local exclusive scan + block totals
__global__ __launch_bounds__(256) void k_scan_blk(const int* __restrict__ deg,
                                                  int* __restrict__ offs,
                                                  int* __restrict__ partials, int N) {
    __shared__ int wsum[4];
    int t = threadIdx.x, lane = t & 63, wid = t >> 6;
    int base = blockIdx.x * 1024 + t * 4;
    int v0 = 0, v1 = 0, v2 = 0, v3 = 0;
    if (base + 3 < N) {
        int4 q = *(const int4*)(deg + base);
        v0 = q.x; v1 = q.y; v2 = q.z; v3 = q.w;
    } else {
        if (base     < N) v0 = deg[base];
        if (base + 1 < N) v1 = deg[base + 1];
        if (base + 2 < N) v2 = deg[base + 2];
        if (base + 3 < N) v3 = deg[base + 3];
    }
    int ts = v0 + v1 + v2 + v3;
    int sc = ts;
    #pragma unroll
    for (int off = 1; off < 64; off <<= 1) {
        int u = __shfl_up(sc, off);
        if (lane >= off) sc += u;
    }
    if (lane == 63) wsum[wid] = sc;
    __syncthreads();
    int wb = 0;
    for (int i = 0; i < wid; ++i) wb += wsum[i];
    int excl = wb + sc - ts;
    if (base     < N) offs[base]     = excl;
    if (base + 1 < N) offs[base + 1] = excl + v0;
    if (base + 2 < N) offs[base + 2] = excl + v0 + v1;
    if (base + 3 < N) offs[base + 3] = excl + v0 + v1 + v2;
    if (t == 255) partials[blockIdx.x] = wb + sc;
}

// phase 2: exclusive-scan the block partials (single wave, chunked)
__global__ __launch_bounds__(64) void k_scan_part(int* __restrict__ partials, int NB) {
    int lane = threadIdx.x;
    int carry = 0;
    for (int b = 0; b < NB; b += 64) {
        int idx = b + lane;
        int v = (idx < NB) ? partials[idx] : 0;
        int sc = v;
        #pragma unroll
        for (int off = 1; off < 64; off <<= 1) {
            int u = __shfl_up(sc, off);
            if (lane >= off) sc += u;
        }
        if (idx < NB) partials[idx] = carry + sc - v;
        carry += __shfl(sc, 63);
    }
    if (lane == 0) partials[NB] = carry;
}

// phase 3: add block base, produce offs + cur, write offs[N]
__global__ void k_scan_add(int* __restrict__ offs, int* __restrict__ cur,
                           const int* __restrict__ partials, int N, int NB) {
    int i = blockIdx.x * 256 + threadIdx.x;
    if (i < N) {
        int v = offs[i] + partials[i >> 10];
        offs[i] = v;
        cur[i] = v;
    }
    if (i == 0) offs[N] = partials[NB];
}

// ---------------------------------------------------------------------------
// Scatter + per-edge softmax weights.
//   pos = cur[c]++; srow[pos] = r;
//   walpha[pos][h] = softmax_h(leaky(d_i[r,h] + d_j[c,h]))
// ---------------------------------------------------------------------------
__global__ __launch_bounds__(256) void k_scatter(const int* __restrict__ rows,
                                                 const int* __restrict__ cols,
                                                 const float* __restrict__ d_i,
                                                 const float* __restrict__ d_j,
                                                 int* __restrict__ cur,
                                                 int* __restrict__ srow,
                                                 float* __restrict__ walpha,
                                                 int E, int N) {
    int e = blockIdx.x * blockDim.x + threadIdx.x;
    if (e >= E + N) return;
    int r, c;
    if (e < E) { r = rows[e]; c = cols[e]; }
    else       { r = e - E;   c = r; }
    int pos = atomicAdd(&cur[c], 1);

    float4 di4 = *(const float4*)(d_i + (size_t)r * HEADS);
    float4 dj4 = *(const float4*)(d_j + (size_t)c * HEADS);
    float l0 = di4.x + dj4.x, l1 = di4.y + dj4.y;
    float l2 = di4.z + dj4.z, l3 = di4.w + dj4.w;
    l0 = l0 > 0.f ? l0 : NEG_SLOPE * l0;
    l1 = l1 > 0.f ? l1 : NEG_SLOPE * l1;
    l2 = l2 > 0.f ? l2 : NEG_SLOPE * l2;
    l3 = l3 > 0.f ? l3 : NEG_SLOPE * l3;
    float m = fmaxf(fmaxf(l0, l1), fmaxf(l2, l3));
    float e0 = __expf(l0 - m), e1 = __expf(l1 - m);
    float e2 = __expf(l2 - m), e3 = __expf(l3 - m);
    float inv = 1.f / (e0 + e1 + e2 + e3);

    srow[pos] = r;
    *(float4*)(walpha + (size_t)pos * HEADS) =
        make_float4(e0 * inv, e1 * inv, e2 * inv, e3 * inv);
}

// ---------------------------------------------------------------------------
// Accumulate: one wave per destination node. Inner loop: gather + fma only.
// ---------------------------------------------------------------------------
__global__ __launch_bounds__(256) void k_accum(const int* __restrict__ offs,
                                               const int* __restrict__ srow,
                                               const float* __restrict__ walpha,
                                               const float* __restrict__ h,
                                               const float* __restrict__ bias,
                                               float* __restrict__ out, int N) {
    int node = blockIdx.x * 4 + (threadIdx.x >> 6);
    if (node >= N) return;
    int c = __builtin_amdgcn_readfirstlane(node);
    int lane = threadIdx.x & 63;
    int head = lane >> 4;

    int s = offs[c], e = offs[c + 1];
    float acc = 0.f;
    int i = s;
    for (; i + 1 < e; i += 2) {
        int r0 = srow[i], r1 = srow[i + 1];
        float w0 = walpha[(size_t)i * HEADS + head];
        float w1 = walpha[(size_t)(i + 1) * HEADS + head];
        float x0 = h[(size_t)r0 * CCH + lane];
        float x1 = h[(size_t)r1 * CCH + lane];
        acc = fmaf(x0, w0, acc);
        acc = fmaf(x1, w1, acc);
    }
    if (i < e) {
        int r = srow[i];
        acc = fmaf(h[(size_t)r * CCH + lane], walpha[(size_t)i * HEADS + head], acc);
    }
    out[(size_t)c * CCH + lane] = acc + bias[lane];
}

extern "C" void kernel_launch(void* const* d_in, const int* in_sizes, int n_in,
                              void* d_out, int out_size, void* d_ws, size_t ws_size,
                              hipStream_t stream) {
    const float* x    = (const float*)d_in[0];
    const int*   ei   = (const int*)  d_in[1];
    const float* w    = (const float*)d_in[2];
    const float* att  = (const float*)d_in[3];
    const float* bias = (const float*)d_in[4];
    float* out = (float*)d_out;

    int N = in_sizes[0] / IN_CH;
    int E = in_sizes[1] / 2;
    const int* rows = ei;
    const int* cols = ei + E;
    int total_e = E + N;
    int NB = (N + 1023) / 1024;
    int Npad = (N + 3) & ~3;

    // workspace carving (256 B aligned slots)
    char* ws = (char*)d_ws;
    auto carve = [&](size_t bytes) {
        char* p = ws;
        ws += (bytes + 255) & ~(size_t)255;
        return p;
    };
    float* h      = (float*)carve((size_t)N * CCH * 4);        // 12.8 MB
    float* di     = (float*)carve((size_t)N * HEADS * 4);      // 0.8 MB
    float* dj     = (float*)carve((size_t)N * HEADS * 4);      // 0.8 MB
    int*   deg    = (int*)  carve((size_t)Npad * 4);
    int*   offs   = (int*)  carve((size_t)(N + 1) * 4);
    int*   cur    = (int*)  carve((size_t)N * 4);
    int*   parts  = (int*)  carve((size_t)(NB + 1) * 4);
    int*   srow   = (int*)  carve((size_t)total_e * 4);        // 3.4 MB
    float* walpha = (float*)carve((size_t)total_e * HEADS * 4);// 13.6 MB

    k_zero<<<(Npad + 255) / 256, 256, 0, stream>>>(deg, Npad);
    k_count<<<(total_e + 255) / 256, 256, 0, stream>>>(cols, deg, E, N);
    k_scan_blk<<<NB, 256, 0, stream>>>(deg, offs, parts, N);
    k_scan_part<<<1, 64, 0, stream>>>(parts, NB);
    k_scan_add<<<(N + 255) / 256, 256, 0, stream>>>(offs, cur, parts, N, NB);
    gat_gemm<<<512, 256, 0, stream>>>(x, w, att, h, di, dj, N);
    k_scatter<<<(total_e + 255) / 256, 256, 0, stream>>>(rows, cols, di, dj, cur,
                                                         srow, walpha, E, N);
    k_accum<<<(N + 3) / 4, 256, 0, stream>>>(offs, srow, walpha, h, bias, out, N);
}

// Round 4
// 170.558 us; speedup vs baseline: 1.8816x; 1.0806x over previous
//
#include <hip/hip_runtime.h>

#define HEADS 4
#define OUT_CH 16
#define CCH 64            // HEADS*OUT_CH
#define IN_CH 128
#define NEG_SLOPE 0.2f

// ---------------------------------------------------------------------------
// GEMM: h[N][64] = x[N][128] @ w[128][64].
// One wave per block; lane = output column. W column held in 128 VGPRs.
// x rows are wave-uniform -> scalar (s_load) traffic on the SMEM pipe.
// 2 rows in flight per wave for ILP. Epilogue: d_i/d_j per-head dots.
// ---------------------------------------------------------------------------
__global__ __launch_bounds__(64, 3) void gat_gemm(const float* __restrict__ x,
                                                  const float* __restrict__ w,
                                                  const float* __restrict__ att,
                                                  float* __restrict__ h,
                                                  float* __restrict__ d_i,
                                                  float* __restrict__ d_j,
                                                  int N, int nwaves) {
    int lane = threadIdx.x;   // 0..63

    float wreg[IN_CH];
    #pragma unroll
    for (int k = 0; k < IN_CH; ++k) wreg[k] = w[k * CCH + lane];

    int head = lane >> 4, ch = lane & 15;
    float ai = att[head * (2 * OUT_CH) + ch];
    float aj = att[head * (2 * OUT_CH) + OUT_CH + ch];

    for (int row0 = blockIdx.x * 2; row0 < N; row0 += nwaves * 2) {
        int r0 = row0;
        int r1 = (row0 + 1 < N) ? row0 + 1 : row0;
        const float* x0 = x + (size_t)r0 * IN_CH;
        const float* x1 = x + (size_t)r1 * IN_CH;

        float a0 = 0.f, a1 = 0.f, a2 = 0.f, a3 = 0.f;
        float b0 = 0.f, b1 = 0.f, b2 = 0.f, b3 = 0.f;
        #pragma unroll
        for (int k = 0; k < IN_CH; k += 4) {
            float p0 = x0[k], p1 = x0[k + 1], p2 = x0[k + 2], p3 = x0[k + 3];
            float q0 = x1[k], q1 = x1[k + 1], q2 = x1[k + 2], q3 = x1[k + 3];
            a0 = fmaf(p0, wreg[k + 0], a0);
            a1 = fmaf(p1, wreg[k + 1], a1);
            a2 = fmaf(p2, wreg[k + 2], a2);
            a3 = fmaf(p3, wreg[k + 3], a3);
            b0 = fmaf(q0, wreg[k + 0], b0);
            b1 = fmaf(q1, wreg[k + 1], b1);
            b2 = fmaf(q2, wreg[k + 2], b2);
            b3 = fmaf(q3, wreg[k + 3], b3);
        }
        float accA = (a0 + a1) + (a2 + a3);
        float accB = (b0 + b1) + (b2 + b3);

        h[(size_t)r0 * CCH + lane] = accA;
        h[(size_t)r1 * CCH + lane] = accB;

        float siA = accA * ai, sjA = accA * aj;
        float siB = accB * ai, sjB = accB * aj;
        #pragma unroll
        for (int off = 1; off < 16; off <<= 1) {
            siA += __shfl_xor(siA, off);
            sjA += __shfl_xor(sjA, off);
            siB += __shfl_xor(siB, off);
            sjB += __shfl_xor(sjB, off);
        }
        if (ch == 0) {
            d_i[r0 * HEADS + head] = siA;
            d_j[r0 * HEADS + head] = sjA;
            d_i[r1 * HEADS + head] = siB;
            d_j[r1 * HEADS + head] = sjB;
        }
    }
}

// ---------------------------------------------------------------------------
// CSR build
// ---------------------------------------------------------------------------
__global__ void k_count(const int* __restrict__ cols, int* __restrict__ deg,
                        int E, int N) {
    int e = blockIdx.x * blockDim.x + threadIdx.x;
    if (e >= E + N) return;
    int c = (e < E) ? cols[e] : (e - E);
    atomicAdd(&deg[c], 1);
}

// phase 1: per-block (1024 elems) local exclusive scan + block totals
__global__ __launch_bounds__(256) void k_scan_blk(const int* __restrict__ deg,
                                                  int* __restrict__ offs,
                                                  int* __restrict__ partials, int N) {
    __shared__ int wsum[4];
    int t = threadIdx.x, lane = t & 63, wid = t >> 6;
    int base = blockIdx.x * 1024 + t * 4;
    int v0 = 0, v1 = 0, v2 = 0, v3 = 0;
    if (base + 3 < N) {
        int4 q = *(const int4*)(deg + base);
        v0 = q.x; v1 = q.y; v2 = q.z; v3 = q.w;
    } else {
        if (base     < N) v0 = deg[base];
        if (base + 1 < N) v1 = deg[base + 1];
        if (base + 2 < N) v2 = deg[base + 2];
        if (base + 3 < N) v3 = deg[base + 3];
    }
    int ts = v0 + v1 + v2 + v3;
    int sc = ts;
    #pragma unroll
    for (int off = 1; off < 64; off <<= 1) {
        int u = __shfl_up(sc, off);
        if (lane >= off) sc += u;
    }
    if (lane == 63) wsum[wid] = sc;
    __syncthreads();
    int wb = 0;
    for (int i = 0; i < wid; ++i) wb += wsum[i];
    int excl = wb + sc - ts;
    if (base     < N) offs[base]     = excl;
    if (base + 1 < N) offs[base + 1] = excl + v0;
    if (base + 2 < N) offs[base + 2] = excl + v0 + v1;
    if (base + 3 < N) offs[base + 3] = excl + v0 + v1 + v2;
    if (t == 255) partials[blockIdx.x] = wb + sc;
}

// phase 2: exclusive-scan the block partials (single wave, chunked)
__global__ __launch_bounds__(64) void k_scan_part(int* __restrict__ partials, int NB) {
    int lane = threadIdx.x;
    int carry = 0;
    for (int b = 0; b < NB; b += 64) {
        int idx = b + lane;
        int v = (idx < NB) ? partials[idx] : 0;
        int sc = v;
        #pragma unroll
        for (int off = 1; off < 64; off <<= 1) {
            int u = __shfl_up(sc, off);
            if (lane >= off) sc += u;
        }
        if (idx < NB) partials[idx] = carry + sc - v;
        carry += __shfl(sc, 63);
    }
    if (lane == 0) partials[NB] = carry;
}

// phase 3: add block base, produce offs + cur, write offs[N]
__global__ void k_scan_add(int* __restrict__ offs, int* __restrict__ cur,
                           const int* __restrict__ partials, int N, int NB) {
    int i = blockIdx.x * 256 + threadIdx.x;
    if (i < N) {
        int v = offs[i] + partials[i >> 10];
        offs[i] = v;
        cur[i] = v;
    }
    if (i == 0) offs[N] = partials[NB];
}

// ---------------------------------------------------------------------------
// Scatter + per-edge softmax weights.
// ---------------------------------------------------------------------------
__global__ __launch_bounds__(256) void k_scatter(const int* __restrict__ rows,
                                                 const int* __restrict__ cols,
                                                 const float* __restrict__ d_i,
                                                 const float* __restrict__ d_j,
                                                 int* __restrict__ cur,
                                                 int* __restrict__ srow,
                                                 float* __restrict__ walpha,
                                                 int E, int N) {
    int e = blockIdx.x * blockDim.x + threadIdx.x;
    if (e >= E + N) return;
    int r, c;
    if (e < E) { r = rows[e]; c = cols[e]; }
    else       { r = e - E;   c = r; }
    int pos = atomicAdd(&cur[c], 1);

    float4 di4 = *(const float4*)(d_i + (size_t)r * HEADS);
    float4 dj4 = *(const float4*)(d_j + (size_t)c * HEADS);
    float l0 = di4.x + dj4.x, l1 = di4.y + dj4.y;
    float l2 = di4.z + dj4.z, l3 = di4.w + dj4.w;
    l0 = l0 > 0.f ? l0 : NEG_SLOPE * l0;
    l1 = l1 > 0.f ? l1 : NEG_SLOPE * l1;
    l2 = l2 > 0.f ? l2 : NEG_SLOPE * l2;
    l3 = l3 > 0.f ? l3 : NEG_SLOPE * l3;
    float m = fmaxf(fmaxf(l0, l1), fmaxf(l2, l3));
    float e0 = __expf(l0 - m), e1 = __expf(l1 - m);
    float e2 = __expf(l2 - m), e3 = __expf(l3 - m);
    float inv = 1.f / (e0 + e1 + e2 + e3);

    srow[pos] = r;
    *(float4*)(walpha + (size_t)pos * HEADS) =
        make_float4(e0 * inv, e1 * inv, e2 * inv, e3 * inv);
}

// ---------------------------------------------------------------------------
// Accumulate: one wave per destination node. Inner loop: gather + fma only.
// ---------------------------------------------------------------------------
__global__ __launch_bounds__(256) void k_accum(const int* __restrict__ offs,
                                               const int* __restrict__ srow,
                                               const float* __restrict__ walpha,
                                               const float* __restrict__ h,
                                               const float* __restrict__ bias,
                                               float* __restrict__ out, int N) {
    int node = blockIdx.x * 4 + (threadIdx.x >> 6);
    if (node >= N) return;
    int c = __builtin_amdgcn_readfirstlane(node);
    int lane = threadIdx.x & 63;
    int head = lane >> 4;

    int s = offs[c], e = offs[c + 1];
    float acc = 0.f;
    int i = s;
    for (; i + 1 < e; i += 2) {
        int r0 = srow[i], r1 = srow[i + 1];
        float w0 = walpha[(size_t)i * HEADS + head];
        float w1 = walpha[(size_t)(i + 1) * HEADS + head];
        float x0 = h[(size_t)r0 * CCH + lane];
        float x1 = h[(size_t)r1 * CCH + lane];
        acc = fmaf(x0, w0, acc);
        acc = fmaf(x1, w1, acc);
    }
    if (i < e) {
        int r = srow[i];
        acc = fmaf(h[(size_t)r * CCH + lane], walpha[(size_t)i * HEADS + head], acc);
    }
    out[(size_t)c * CCH + lane] = acc + bias[lane];
}

extern "C" void kernel_launch(void* const* d_in, const int* in_sizes, int n_in,
                              void* d_out, int out_size, void* d_ws, size_t ws_size,
                              hipStream_t stream) {
    const float* x    = (const float*)d_in[0];
    const int*   ei   = (const int*)  d_in[1];
    const float* w    = (const float*)d_in[2];
    const float* att  = (const float*)d_in[3];
    const float* bias = (const float*)d_in[4];
    float* out = (float*)d_out;

    int N = in_sizes[0] / IN_CH;
    int E = in_sizes[1] / 2;
    const int* rows = ei;
    const int* cols = ei + E;
    int total_e = E + N;
    int NB = (N + 1023) / 1024;
    int Npad = (N + 3) & ~3;

    // workspace carving (256 B aligned slots)
    char* ws = (char*)d_ws;
    auto carve = [&](size_t bytes) {
        char* p = ws;
        ws += (bytes + 255) & ~(size_t)255;
        return p;
    };
    float* h      = (float*)carve((size_t)N * CCH * 4);        // 12.8 MB
    float* di     = (float*)carve((size_t)N * HEADS * 4);      // 0.8 MB
    float* dj     = (float*)carve((size_t)N * HEADS * 4);      // 0.8 MB
    int*   deg    = (int*)  carve((size_t)Npad * 4);
    int*   offs   = (int*)  carve((size_t)(N + 1) * 4);
    int*   cur    = (int*)  carve((size_t)N * 4);
    int*   parts  = (int*)  carve((size_t)(NB + 1) * 4);
    int*   srow   = (int*)  carve((size_t)total_e * 4);        // 3.4 MB
    float* walpha = (float*)carve((size_t)total_e * HEADS * 4);// 13.6 MB

    const int NWAVES = 3072;   // 3 waves/SIMD device-fill

    hipMemsetAsync(deg, 0, (size_t)Npad * 4, stream);
    k_count<<<(total_e + 255) / 256, 256, 0, stream>>>(cols, deg, E, N);
    k_scan_blk<<<NB, 256, 0, stream>>>(deg, offs, parts, N);
    k_scan_part<<<1, 64, 0, stream>>>(parts, NB);
    k_scan_add<<<(N + 255) / 256, 256, 0, stream>>>(offs, cur, parts, N, NB);
    gat_gemm<<<NWAVES, 64, 0, stream>>>(x, w, att, h, di, dj, N, NWAVES);
    k_scatter<<<(total_e + 255) / 256, 256, 0, stream>>>(rows, cols, di, dj, cur,
                                                         srow, walpha, E, N);
    k_accum<<<(N + 3) / 4, 256, 0, stream>>>(offs, srow, walpha, h, bias, out, N);
}

// Round 5
// 157.130 us; speedup vs baseline: 2.0425x; 1.0855x over previous
//
#include <hip/hip_runtime.h>

#define HEADS 4
#define OUT_CH 16
#define CCH 64            // HEADS*OUT_CH
#define IN_CH 128
#define NEG_SLOPE 0.2f

// ---------------------------------------------------------------------------
// GEMM: h[N][64] = x[N][128] @ w[128][64].
// One wave per block; lane = output column. W column held in 128 *named*
// scalars (forced VGPR residency; arrays were demoted to L2 re-loads).
// x rows are wave-uniform -> scalar loads. 2 rows in flight for ILP.
// ---------------------------------------------------------------------------
#define W_INIT(K, A, B, C, D) \
    float A = wp[(K) * CCH], B = wp[(K + 1) * CCH], \
          C = wp[(K + 2) * CCH], D = wp[(K + 3) * CCH];

#define STEP(K, A, B, C, D) { \
    float4 p = *(const float4*)(x0 + (K)); \
    float4 q = *(const float4*)(x1 + (K)); \
    a0 = fmaf(p.x, A, a0); a1 = fmaf(p.y, B, a1); \
    a2 = fmaf(p.z, C, a2); a3 = fmaf(p.w, D, a3); \
    b0 = fmaf(q.x, A, b0); b1 = fmaf(q.y, B, b1); \
    b2 = fmaf(q.z, C, b2); b3 = fmaf(q.w, D, b3); }

__global__ __launch_bounds__(64, 2) void gat_gemm(const float* __restrict__ x,
                                                  const float* __restrict__ w,
                                                  const float* __restrict__ att,
                                                  float* __restrict__ h,
                                                  float* __restrict__ d_i,
                                                  float* __restrict__ d_j,
                                                  int N, int nwaves) {
    int lane = threadIdx.x;   // 0..63
    const float* wp = w + lane;

    W_INIT(0,   w0,  w1,  w2,  w3)   W_INIT(4,   w4,  w5,  w6,  w7)
    W_INIT(8,   w8,  w9,  w10, w11)  W_INIT(12,  w12, w13, w14, w15)
    W_INIT(16,  w16, w17, w18, w19)  W_INIT(20,  w20, w21, w22, w23)
    W_INIT(24,  w24, w25, w26, w27)  W_INIT(28,  w28, w29, w30, w31)
    W_INIT(32,  w32, w33, w34, w35)  W_INIT(36,  w36, w37, w38, w39)
    W_INIT(40,  w40, w41, w42, w43)  W_INIT(44,  w44, w45, w46, w47)
    W_INIT(48,  w48, w49, w50, w51)  W_INIT(52,  w52, w53, w54, w55)
    W_INIT(56,  w56, w57, w58, w59)  W_INIT(60,  w60, w61, w62, w63)
    W_INIT(64,  w64, w65, w66, w67)  W_INIT(68,  w68, w69, w70, w71)
    W_INIT(72,  w72, w73, w74, w75)  W_INIT(76,  w76, w77, w78, w79)
    W_INIT(80,  w80, w81, w82, w83)  W_INIT(84,  w84, w85, w86, w87)
    W_INIT(88,  w88, w89, w90, w91)  W_INIT(92,  w92, w93, w94, w95)
    W_INIT(96,  w96, w97, w98, w99)  W_INIT(100, w100,w101,w102,w103)
    W_INIT(104, w104,w105,w106,w107) W_INIT(108, w108,w109,w110,w111)
    W_INIT(112, w112,w113,w114,w115) W_INIT(116, w116,w117,w118,w119)
    W_INIT(120, w120,w121,w122,w123) W_INIT(124, w124,w125,w126,w127)

    int head = lane >> 4, ch = lane & 15;
    float ai = att[head * (2 * OUT_CH) + ch];
    float aj = att[head * (2 * OUT_CH) + OUT_CH + ch];

    for (int row0 = blockIdx.x * 2; row0 < N; row0 += nwaves * 2) {
        int r0 = __builtin_amdgcn_readfirstlane(row0);
        int r1 = (r0 + 1 < N) ? r0 + 1 : r0;
        const float* x0 = x + (size_t)r0 * IN_CH;
        const float* x1 = x + (size_t)r1 * IN_CH;

        float a0 = 0.f, a1 = 0.f, a2 = 0.f, a3 = 0.f;
        float b0 = 0.f, b1 = 0.f, b2 = 0.f, b3 = 0.f;

        STEP(0,   w0,  w1,  w2,  w3)   STEP(4,   w4,  w5,  w6,  w7)
        STEP(8,   w8,  w9,  w10, w11)  STEP(12,  w12, w13, w14, w15)
        STEP(16,  w16, w17, w18, w19)  STEP(20,  w20, w21, w22, w23)
        STEP(24,  w24, w25, w26, w27)  STEP(28,  w28, w29, w30, w31)
        STEP(32,  w32, w33, w34, w35)  STEP(36,  w36, w37, w38, w39)
        STEP(40,  w40, w41, w42, w43)  STEP(44,  w44, w45, w46, w47)
        STEP(48,  w48, w49, w50, w51)  STEP(52,  w52, w53, w54, w55)
        STEP(56,  w56, w57, w58, w59)  STEP(60,  w60, w61, w62, w63)
        STEP(64,  w64, w65, w66, w67)  STEP(68,  w68, w69, w70, w71)
        STEP(72,  w72, w73, w74, w75)  STEP(76,  w76, w77, w78, w79)
        STEP(80,  w80, w81, w82, w83)  STEP(84,  w84, w85, w86, w87)
        STEP(88,  w88, w89, w90, w91)  STEP(92,  w92, w93, w94, w95)
        STEP(96,  w96, w97, w98, w99)  STEP(100, w100,w101,w102,w103)
        STEP(104, w104,w105,w106,w107) STEP(108, w108,w109,w110,w111)
        STEP(112, w112,w113,w114,w115) STEP(116, w116,w117,w118,w119)
        STEP(120, w120,w121,w122,w123) STEP(124, w124,w125,w126,w127)

        float accA = (a0 + a1) + (a2 + a3);
        float accB = (b0 + b1) + (b2 + b3);

        h[(size_t)r0 * CCH + lane] = accA;
        h[(size_t)r1 * CCH + lane] = accB;

        float siA = accA * ai, sjA = accA * aj;
        float siB = accB * ai, sjB = accB * aj;
        #pragma unroll
        for (int off = 1; off < 16; off <<= 1) {
            siA += __shfl_xor(siA, off);
            sjA += __shfl_xor(sjA, off);
            siB += __shfl_xor(siB, off);
            sjB += __shfl_xor(sjB, off);
        }
        if (ch == 0) {
            d_i[r0 * HEADS + head] = siA;
            d_j[r0 * HEADS + head] = sjA;
            d_i[r1 * HEADS + head] = siB;
            d_j[r1 * HEADS + head] = sjB;
        }
    }
}

// ---------------------------------------------------------------------------
// Rank + per-edge alpha (coalesced writes). rank[e] = order within dest c.
// ---------------------------------------------------------------------------
__global__ __launch_bounds__(256) void k_rank_alpha(const int* __restrict__ rows,
                                                    const int* __restrict__ cols,
                                                    const float* __restrict__ d_i,
                                                    const float* __restrict__ d_j,
                                                    int* __restrict__ deg,
                                                    int* __restrict__ rank,
                                                    float* __restrict__ walpha_e,
                                                    int E, int N) {
    int e = blockIdx.x * blockDim.x + threadIdx.x;
    if (e >= E + N) return;
    int r, c;
    if (e < E) { r = rows[e]; c = cols[e]; }
    else       { r = e - E;   c = r; }

    rank[e] = atomicAdd(&deg[c], 1);

    float4 di4 = *(const float4*)(d_i + (size_t)r * HEADS);
    float4 dj4 = *(const float4*)(d_j + (size_t)c * HEADS);
    float l0 = di4.x + dj4.x, l1 = di4.y + dj4.y;
    float l2 = di4.z + dj4.z, l3 = di4.w + dj4.w;
    l0 = l0 > 0.f ? l0 : NEG_SLOPE * l0;
    l1 = l1 > 0.f ? l1 : NEG_SLOPE * l1;
    l2 = l2 > 0.f ? l2 : NEG_SLOPE * l2;
    l3 = l3 > 0.f ? l3 : NEG_SLOPE * l3;
    float m = fmaxf(fmaxf(l0, l1), fmaxf(l2, l3));
    float e0 = __expf(l0 - m), e1 = __expf(l1 - m);
    float e2 = __expf(l2 - m), e3 = __expf(l3 - m);
    float inv = 1.f / (e0 + e1 + e2 + e3);
    *(float4*)(walpha_e + (size_t)e * HEADS) =
        make_float4(e0 * inv, e1 * inv, e2 * inv, e3 * inv);
}

// ---------------------------------------------------------------------------
// Scan: block-local -> partials -> add (no atomics, no cur needed)
// ---------------------------------------------------------------------------
__global__ __launch_bounds__(256) void k_scan_blk(const int* __restrict__ deg,
                                                  int* __restrict__ offs,
                                                  int* __restrict__ partials, int N) {
    __shared__ int wsum[4];
    int t = threadIdx.x, lane = t & 63, wid = t >> 6;
    int base = blockIdx.x * 1024 + t * 4;
    int v0 = 0, v1 = 0, v2 = 0, v3 = 0;
    if (base + 3 < N) {
        int4 q = *(const int4*)(deg + base);
        v0 = q.x; v1 = q.y; v2 = q.z; v3 = q.w;
    } else {
        if (base     < N) v0 = deg[base];
        if (base + 1 < N) v1 = deg[base + 1];
        if (base + 2 < N) v2 = deg[base + 2];
        if (base + 3 < N) v3 = deg[base + 3];
    }
    int ts = v0 + v1 + v2 + v3;
    int sc = ts;
    #pragma unroll
    for (int off = 1; off < 64; off <<= 1) {
        int u = __shfl_up(sc, off);
        if (lane >= off) sc += u;
    }
    if (lane == 63) wsum[wid] = sc;
    __syncthreads();
    int wb = 0;
    for (int i = 0; i < wid; ++i) wb += wsum[i];
    int excl = wb + sc - ts;
    if (base     < N) offs[base]     = excl;
    if (base + 1 < N) offs[base + 1] = excl + v0;
    if (base + 2 < N) offs[base + 2] = excl + v0 + v1;
    if (base + 3 < N) offs[base + 3] = excl + v0 + v1 + v2;
    if (t == 255) partials[blockIdx.x] = wb + sc;
}

__global__ __launch_bounds__(64) void k_scan_part(int* __restrict__ partials, int NB) {
    int lane = threadIdx.x;
    int carry = 0;
    for (int b = 0; b < NB; b += 64) {
        int idx = b + lane;
        int v = (idx < NB) ? partials[idx] : 0;
        int sc = v;
        #pragma unroll
        for (int off = 1; off < 64; off <<= 1) {
            int u = __shfl_up(sc, off);
            if (lane >= off) sc += u;
        }
        if (idx < NB) partials[idx] = carry + sc - v;
        carry += __shfl(sc, 63);
    }
    if (lane == 0) partials[NB] = carry;
}

__global__ void k_scan_add(int* __restrict__ offs,
                           const int* __restrict__ partials, int N, int NB) {
    int i = blockIdx.x * 256 + threadIdx.x;
    if (i < N) offs[i] += partials[i >> 10];
    if (i == 0) offs[N] = partials[NB];
}

// ---------------------------------------------------------------------------
// Atomic-free scatter: pos = offs[c] + rank[e]; 8 B per edge.
// ---------------------------------------------------------------------------
__global__ __launch_bounds__(256) void k_scatter2(const int* __restrict__ rows,
                                                  const int* __restrict__ cols,
                                                  const int* __restrict__ offs,
                                                  const int* __restrict__ rank,
                                                  int* __restrict__ srow,
                                                  int* __restrict__ sedge,
                                                  int E, int N) {
    int e = blockIdx.x * blockDim.x + threadIdx.x;
    if (e >= E + N) return;
    int r, c;
    if (e < E) { r = rows[e]; c = cols[e]; }
    else       { r = e - E;   c = r; }
    int pos = offs[c] + rank[e];
    srow[pos] = r;
    sedge[pos] = e;
}

// ---------------------------------------------------------------------------
// Accumulate: one wave per destination node. gather + fma only.
// ---------------------------------------------------------------------------
__global__ __launch_bounds__(256) void k_accum(const int* __restrict__ offs,
                                               const int* __restrict__ srow,
                                               const int* __restrict__ sedge,
                                               const float* __restrict__ walpha_e,
                                               const float* __restrict__ h,
                                               const float* __restrict__ bias,
                                               float* __restrict__ out, int N) {
    int node = blockIdx.x * 4 + (threadIdx.x >> 6);
    if (node >= N) return;
    int c = __builtin_amdgcn_readfirstlane(node);
    int lane = threadIdx.x & 63;
    int head = lane >> 4;

    int s = offs[c], e = offs[c + 1];
    float acc = 0.f;
    int i = s;
    for (; i + 1 < e; i += 2) {
        int r0 = srow[i], r1 = srow[i + 1];
        int e0 = sedge[i], e1 = sedge[i + 1];
        float w0 = walpha_e[(size_t)e0 * HEADS + head];
        float w1 = walpha_e[(size_t)e1 * HEADS + head];
        float x0 = h[(size_t)r0 * CCH + lane];
        float x1 = h[(size_t)r1 * CCH + lane];
        acc = fmaf(x0, w0, acc);
        acc = fmaf(x1, w1, acc);
    }
    if (i < e) {
        int r = srow[i];
        int e0 = sedge[i];
        acc = fmaf(h[(size_t)r * CCH + lane], walpha_e[(size_t)e0 * HEADS + head], acc);
    }
    out[(size_t)c * CCH + lane] = acc + bias[lane];
}

extern "C" void kernel_launch(void* const* d_in, const int* in_sizes, int n_in,
                              void* d_out, int out_size, void* d_ws, size_t ws_size,
                              hipStream_t stream) {
    const float* x    = (const float*)d_in[0];
    const int*   ei   = (const int*)  d_in[1];
    const float* w    = (const float*)d_in[2];
    const float* att  = (const float*)d_in[3];
    const float* bias = (const float*)d_in[4];
    float* out = (float*)d_out;

    int N = in_sizes[0] / IN_CH;
    int E = in_sizes[1] / 2;
    const int* rows = ei;
    const int* cols = ei + E;
    int total_e = E + N;
    int NB = (N + 1023) / 1024;
    int Npad = (N + 3) & ~3;

    char* ws = (char*)d_ws;
    auto carve = [&](size_t bytes) {
        char* p = ws;
        ws += (bytes + 255) & ~(size_t)255;
        return p;
    };
    float* h        = (float*)carve((size_t)N * CCH * 4);          // 12.8 MB
    float* di       = (float*)carve((size_t)N * HEADS * 4);        // 0.8 MB
    float* dj       = (float*)carve((size_t)N * HEADS * 4);        // 0.8 MB
    int*   deg      = (int*)  carve((size_t)Npad * 4);
    int*   offs     = (int*)  carve((size_t)(N + 1) * 4);
    int*   parts    = (int*)  carve((size_t)(NB + 1) * 4);
    int*   rank     = (int*)  carve((size_t)total_e * 4);          // 3.4 MB
    int*   srow     = (int*)  carve((size_t)total_e * 4);          // 3.4 MB
    int*   sedge    = (int*)  carve((size_t)total_e * 4);          // 3.4 MB
    float* walpha_e = (float*)carve((size_t)total_e * HEADS * 4);  // 13.6 MB

    const int NWAVES = 3072;

    hipMemsetAsync(deg, 0, (size_t)Npad * 4, stream);
    gat_gemm<<<NWAVES, 64, 0, stream>>>(x, w, att, h, di, dj, N, NWAVES);
    k_rank_alpha<<<(total_e + 255) / 256, 256, 0, stream>>>(rows, cols, di, dj,
                                                            deg, rank, walpha_e, E, N);
    k_scan_blk<<<NB, 256, 0, stream>>>(deg, offs, parts, N);
    k_scan_part<<<1, 64, 0, stream>>>(parts, NB);
    k_scan_add<<<(N + 255) / 256, 256, 0, stream>>>(offs, parts, N, NB);
    k_scatter2<<<(total_e + 255) / 256, 256, 0, stream>>>(rows, cols, offs, rank,
                                                          srow, sedge, E, N);
    k_accum<<<(N + 3) / 4, 256, 0, stream>>>(offs, srow, sedge, walpha_e, h, bias, out, N);
}